// Round 8
// baseline (281.735 us; speedup 1.0000x reference)
//
#include <hip/hip_runtime.h>

typedef __attribute__((ext_vector_type(8))) short short8;
typedef __attribute__((ext_vector_type(4))) float f32x4;

#define INF 4096

#define AS1 __attribute__((address_space(1)))
#define AS3 __attribute__((address_space(3)))

__device__ __forceinline__ unsigned short f2bf(float f) {
    unsigned int u = __float_as_uint(f);
    u += 0x7FFFu + ((u >> 16) & 1u);
    return (unsigned short)(u >> 16);
}

__device__ __forceinline__ void gl_lds16(const unsigned short* g, void* l) {
    __builtin_amdgcn_global_load_lds((const AS1 void*)g, (AS3 void*)l, 16, 0, 0);
}

// swizzle within a 16KB half-tile [128 rows][64 bf16] (128B rows):
// XOR byte bits {4,5,6} with row bits {0,1,2}. Involution, 16B-preserving.
__device__ __forceinline__ int swz7(int b) { return b ^ ((b >> 3) & 0x70); }
// 64B-row variant used by the fallback kernel (R4/R5-verified, 0 conflicts)
__device__ __forceinline__ int swz6(int b) { return b ^ ((b >> 3) & 0x30); }

#define BAR()   __builtin_amdgcn_s_barrier()
#define SB0()   __builtin_amdgcn_sched_barrier(0)
#define LGKM0() { asm volatile("s_waitcnt lgkmcnt(0)" ::: "memory"); __builtin_amdgcn_sched_barrier(0); }

// ---------------- prepass: fp32 -> bf16 for x and hw ----------------
__global__ __launch_bounds__(256)
void cvt_bf16(const float* __restrict__ x, const float* __restrict__ hw,
              unsigned short* __restrict__ xb, unsigned short* __restrict__ wb)
{
    const long long NX = 8192LL * 4096;
    const long long NW = 5LL * 16 * 256 * 256;
    const long long total8 = (NX + NW) / 8;
    for (long long i = (long long)blockIdx.x * 256 + threadIdx.x; i < total8;
         i += (long long)gridDim.x * 256) {
        long long e = i * 8;
        const float* src;
        unsigned short* dst;
        long long off;
        if (e < NX) { src = x;  dst = xb; off = e; }
        else        { src = hw; dst = wb; off = e - NX; }
        float4 f0 = *(const float4*)(src + off);
        float4 f1 = *(const float4*)(src + off + 4);
        ushort4 u0, u1;
        u0.x = f2bf(f0.x); u0.y = f2bf(f0.y); u0.z = f2bf(f0.z); u0.w = f2bf(f0.w);
        u1.x = f2bf(f1.x); u1.y = f2bf(f1.y); u1.z = f2bf(f1.z); u1.w = f2bf(f1.w);
        *(ushort4*)(dst + off)     = u0;
        *(ushort4*)(dst + off + 4) = u1;
    }
}

// ======== main GEMM: 256x256 tile, 8 waves, BK=64, 8-phase counted-vmcnt ========
// LDS (byte): buf(kt&1)*65536 + reg*16384; reg: 0=A0(rows0-127),1=A1,2=B0,3=B1.
// Regions are PER-WAVE-FIXED (wr -> A half, wcn>>1 -> B half); LDA/LDB pick rows
// within the wave's region. Region retirement (all waves, after closing BAR):
//   buf0: B at P1 (fb0 kept in regs for P3), A at P2.  buf1: B at P5, A at P6.
// Stage slots (one phase after retirement, WAR-safe):
//   P0: T_o.A1 | P2: T_e+2.B0 | P3: T_e+2.{A0,B1} +gate | P4: T_e+2.A1
//   P6: T_o+2.B0 | P7: T_o+2.{A0,B1} +gate
// Gates: 14 loads outstanding at each -> vmcnt(6) completes the needed tile,
// leaves 3 halves (6 loads) in flight; youngest gated half has 3-phase slack.
// Tail (i=9): vmcnt(0) at both gates (vmcnt(6) would be a no-op -> race).
__global__ __launch_bounds__(512, 2)
void hcl_gemm8p(const unsigned short* __restrict__ xb,
                const unsigned short* __restrict__ wb,
                const float* __restrict__ hb,
                float* __restrict__ out)
{
    extern __shared__ char lds[];   // 131072

    const int tid  = threadIdx.x;       // 0..511
    const int lane = tid & 63;
    const int wave = tid >> 6;          // 0..7
    const int wr   = wave >> 2;         // 0..1  m-half
    const int wcn  = wave & 3;          // 0..3  n-quarter
    const int ln15 = lane & 15;
    const int hi   = lane >> 4;

    const int bm0 = blockIdx.x * 256;
    const int p   = blockIdx.y;

    int offA[8], offB[4];
    #pragma unroll
    for (int mf = 0; mf < 8; ++mf)
        offA[mf] = wr * 16384 + swz7((mf * 16 + ln15) * 128 + hi * 16);
    #pragma unroll
    for (int nf = 0; nf < 4; ++nf)
        offB[nf] = 32768 + (wcn >> 1) * 16384 +
                   swz7(((wcn & 1) * 64 + nf * 16 + ln15) * 128 + hi * 16);

    int srow[2], skcol[2];
    #pragma unroll
    for (int j = 0; j < 2; ++j) {
        int L = swz7(j * 8192 + tid * 16);
        srow[j]  = L >> 7;
        skcol[j] = (L & 127) >> 1;
    }

    f32x4 acc[8][4] = {};

    auto STAGE = [&](int kt, int reg) {   // reg: 0=A0,1=A1,2=B0,3=B1
        if (kt >= 20) return;
        const int t  = kt >> 2;
        const int s  = p ^ ((1 << t) >> 1);
        const int k0 = (kt & 3) * 64;
        char* dst = lds + (kt & 1) * 65536 + reg * 16384 + tid * 16;
        if (reg < 2) {
            const unsigned short* g = xb + (size_t)(bm0 + reg * 128) * INF + s * 256 + k0;
            gl_lds16(g + (size_t)srow[0] * INF + skcol[0], dst);
            gl_lds16(g + (size_t)srow[1] * INF + skcol[1], dst + 8192);
        } else {
            const unsigned short* g = wb + ((size_t)(t * 16 + s) << 16) + (reg - 2) * 32768 + k0;
            gl_lds16(g + (size_t)srow[0] * 256 + skcol[0], dst);
            gl_lds16(g + (size_t)srow[1] * 256 + skcol[1], dst + 8192);
        }
    };

    short8 fa[8], fb0[4], fb1[4];
    auto LDA = [&](int qm, int buf) {      // 8 reads into fa
        const char* L = lds + buf * 65536;
        #pragma unroll
        for (int m = 0; m < 4; ++m) {
            fa[m * 2 + 0] = *(const short8*)(L + offA[qm * 4 + m]);
            fa[m * 2 + 1] = *(const short8*)(L + (offA[qm * 4 + m] ^ 64));
        }
    };
    auto LDB0 = [&](int buf) {             // qn0 -> fb0 (kept live P0..P3)
        const char* L = lds + buf * 65536;
        #pragma unroll
        for (int n = 0; n < 2; ++n) {
            fb0[n * 2 + 0] = *(const short8*)(L + offB[n]);
            fb0[n * 2 + 1] = *(const short8*)(L + (offB[n] ^ 64));
        }
    };
    auto LDB1 = [&](int buf) {             // qn1 -> fb1
        const char* L = lds + buf * 65536;
        #pragma unroll
        for (int n = 0; n < 2; ++n) {
            fb1[n * 2 + 0] = *(const short8*)(L + offB[2 + n]);
            fb1[n * 2 + 1] = *(const short8*)(L + (offB[2 + n] ^ 64));
        }
    };
    auto MM0 = [&](int qm) {               // quadrant (qm, qn0) with fb0
        __builtin_amdgcn_s_setprio(1);
        #pragma unroll
        for (int m = 0; m < 4; ++m)
            #pragma unroll
            for (int n = 0; n < 2; ++n)
                #pragma unroll
                for (int ks = 0; ks < 2; ++ks)
                    acc[qm * 4 + m][n] = __builtin_amdgcn_mfma_f32_16x16x32_bf16(
                        fa[m * 2 + ks], fb0[n * 2 + ks], acc[qm * 4 + m][n], 0, 0, 0);
        __builtin_amdgcn_s_setprio(0);
    };
    auto MM1 = [&](int qm) {               // quadrant (qm, qn1) with fb1
        __builtin_amdgcn_s_setprio(1);
        #pragma unroll
        for (int m = 0; m < 4; ++m)
            #pragma unroll
            for (int n = 0; n < 2; ++n)
                #pragma unroll
                for (int ks = 0; ks < 2; ++ks)
                    acc[qm * 4 + m][2 + n] = __builtin_amdgcn_mfma_f32_16x16x32_bf16(
                        fa[m * 2 + ks], fb1[n * 2 + ks], acc[qm * 4 + m][2 + n], 0, 0, 0);
        __builtin_amdgcn_s_setprio(0);
    };

    // prologue: T0 all (8 loads) + T1.{B0,A0,B1} (6 loads); vmcnt(6) -> T0 landed
    STAGE(0, 0); STAGE(0, 1); STAGE(0, 2); STAGE(0, 3);
    STAGE(1, 2); STAGE(1, 0); STAGE(1, 3);
    asm volatile("s_waitcnt vmcnt(6)" ::: "memory");
    BAR(); SB0();

    for (int i = 0; i < 10; ++i) {
        const int To  = 2 * i + 1;   // odd tile (buf1), computed P4-P7
        const int Te2 = 2 * i + 2;   // next even tile (buf0)
        const int To2 = 2 * i + 3;   // next odd tile (buf1)
        const bool last = (i == 9);
        // P0: buf0 (qm0,qn0); stage To.A1 (buf1.A retired prev P6)
        LDA(0, 0); LDB0(0); STAGE(To, 1);
        BAR(); LGKM0(); MM0(0); BAR(); SB0();
        // P1: buf0 (qm0,qn1)
        LDB1(0);
        BAR(); LGKM0(); MM1(0); BAR(); SB0();
        // P2: buf0 (qm1,qn1); stage Te2.B0 (buf0.B retired P1)
        LDA(1, 0); STAGE(Te2, 2);
        BAR(); LGKM0(); MM1(1); BAR(); SB0();
        // P3: buf0 (qm1,qn0) from regs; stage Te2.{A0,B1} (buf0.A retired P2);
        //     gate: T1..To complete
        STAGE(Te2, 0); STAGE(Te2, 3);
        if (last) { asm volatile("s_waitcnt vmcnt(0)" ::: "memory"); }
        else      { asm volatile("s_waitcnt vmcnt(6)" ::: "memory"); }
        BAR(); LGKM0(); MM0(1); BAR(); SB0();
        // P4: buf1 (qm0,qn0); stage Te2.A1
        LDA(0, 1); LDB0(1); STAGE(Te2, 1);
        BAR(); LGKM0(); MM0(0); BAR(); SB0();
        // P5: buf1 (qm0,qn1)
        LDB1(1);
        BAR(); LGKM0(); MM1(0); BAR(); SB0();
        // P6: buf1 (qm1,qn1); stage To2.B0 (buf1.B retired P5)
        LDA(1, 1); STAGE(To2, 2);
        BAR(); LGKM0(); MM1(1); BAR(); SB0();
        // P7: buf1 (qm1,qn0) from regs; stage To2.{A0,B1} (buf1.A retired P6);
        //     gate: Te2 complete
        STAGE(To2, 0); STAGE(To2, 3);
        if (last) { asm volatile("s_waitcnt vmcnt(0)" ::: "memory"); }
        else      { asm volatile("s_waitcnt vmcnt(6)" ::: "memory"); }
        BAR(); LGKM0(); MM0(1); BAR(); SB0();
    }

    // epilogue: C/D layout col = lane&15, row = (lane>>4)*4 + r  [R4-verified]
    const int col0 = p * 256 + wcn * 64;
    #pragma unroll
    for (int nf = 0; nf < 4; ++nf) {
        const int col = col0 + nf * 16 + ln15;
        const float bias = hb[col];
        #pragma unroll
        for (int mf = 0; mf < 8; ++mf) {
            #pragma unroll
            for (int r = 0; r < 4; ++r) {
                const int row = bm0 + wr * 128 + mf * 16 + hi * 4 + r;
                out[(size_t)row * 4096 + col] = acc[mf][nf][r] + bias;
            }
        }
    }
}

// -------- fallback GEMM (R5, proven): 128x256 tile, 4 waves, 3-buffer --------
#define NKT4 40
#define BUFB4 24576
__global__ __launch_bounds__(256, 2)
void hcl_gemm4(const unsigned short* __restrict__ xb,
               const unsigned short* __restrict__ wb,
               const float* __restrict__ hb,
               float* __restrict__ out)
{
    extern __shared__ unsigned short lds4[];

    const int tid  = threadIdx.x;
    const int lane = tid & 63;
    const int wave = tid >> 6;
    const int ln15 = lane & 15;
    const int hi   = lane >> 4;

    const int bm0 = blockIdx.x * 128;
    const int p   = blockIdx.y;

    int rj[4], cj[4];
    #pragma unroll
    for (int j = 0; j < 4; ++j) {
        int g = swz6(j * 4096 + tid * 16);
        rj[j] = g >> 6;
        cj[j] = (g & 63) >> 1;
    }

    int offA[8], offB[4];
    #pragma unroll
    for (int mf = 0; mf < 8; ++mf)
        offA[mf] = swz6((mf * 16 + ln15) * 64 + hi * 16);
    #pragma unroll
    for (int nf = 0; nf < 4; ++nf)
        offB[nf] = swz6((wave * 64 + nf * 16 + ln15) * 64 + hi * 16);

    f32x4 acc[8][4] = {};

    auto STAGE = [&](int kt, int buf) {
        const int t = kt >> 3;
        const int s = p ^ ((1 << t) >> 1);
        const unsigned short* ga = xb + (size_t)bm0 * INF + s * 256 + (kt & 7) * 32;
        const unsigned short* gb = wb + ((size_t)(t * 16 + s) << 16) + (kt & 7) * 32;
        char* lb = (char*)lds4 + buf * BUFB4 + wave * 1024;
        gl_lds16(ga + (size_t)rj[0] * INF + cj[0], lb);
        gl_lds16(ga + (size_t)rj[1] * INF + cj[1], lb + 4096);
        gl_lds16(gb + (size_t)rj[0] * 256 + cj[0], lb + 8192);
        gl_lds16(gb + (size_t)rj[1] * 256 + cj[1], lb + 8192 + 4096);
        gl_lds16(gb + (size_t)rj[2] * 256 + cj[2], lb + 8192 + 8192);
        gl_lds16(gb + (size_t)rj[3] * 256 + cj[3], lb + 8192 + 12288);
    };

    auto COMPUTE = [&](int buf) {
        const char* LA = (const char*)lds4 + buf * BUFB4;
        const char* LB = LA + 8192;
        short8 fa[8], fb[4];
        #pragma unroll
        for (int nf = 0; nf < 4; ++nf) fb[nf] = *(const short8*)(LB + offB[nf]);
        #pragma unroll
        for (int mf = 0; mf < 8; ++mf) fa[mf] = *(const short8*)(LA + offA[mf]);
        __builtin_amdgcn_s_setprio(1);
        #pragma unroll
        for (int mf = 0; mf < 8; ++mf)
            #pragma unroll
            for (int nf = 0; nf < 4; ++nf)
                acc[mf][nf] = __builtin_amdgcn_mfma_f32_16x16x32_bf16(
                    fa[mf], fb[nf], acc[mf][nf], 0, 0, 0);
        __builtin_amdgcn_s_setprio(0);
    };

    STAGE(0, 0);
    STAGE(1, 1);
    for (int kt = 0; kt < NKT4 - 2; ++kt) {
        STAGE(kt + 2, (kt + 2) % 3);
        asm volatile("s_waitcnt vmcnt(12)" ::: "memory");
        BAR(); SB0();
        COMPUTE(kt % 3);
        BAR(); SB0();
    }
    asm volatile("s_waitcnt vmcnt(6)" ::: "memory");
    BAR(); SB0();
    COMPUTE((NKT4 - 2) % 3);
    BAR(); SB0();
    asm volatile("s_waitcnt vmcnt(0)" ::: "memory");
    BAR(); SB0();
    COMPUTE((NKT4 - 1) % 3);

    const int col0 = p * 256 + wave * 64;
    #pragma unroll
    for (int nf = 0; nf < 4; ++nf) {
        const int col = col0 + nf * 16 + ln15;
        const float bias = hb[col];
        #pragma unroll
        for (int mf = 0; mf < 8; ++mf) {
            #pragma unroll
            for (int r = 0; r < 4; ++r) {
                const int row = bm0 + mf * 16 + hi * 4 + r;
                out[(size_t)row * 4096 + col] = acc[mf][nf][r] + bias;
            }
        }
    }
}

// ---------------- fallback (fused) if ws too small ----------------
__global__ __launch_bounds__(256)
void hcl_mfma_fused(const float* __restrict__ x,
                    const float* __restrict__ hw,
                    const float* __restrict__ hb,
                    float* __restrict__ out)
{
    __shared__ unsigned short As[128][32];
    __shared__ unsigned short Bs[128][32];

    const int tid  = threadIdx.x;
    const int lane = tid & 63;
    const int wave = tid >> 6;
    const int wr   = wave >> 1, wc = wave & 1;

    const int bm0 = blockIdx.x * 128;
    const int p   = blockIdx.y >> 1;
    const int nh  = blockIdx.y & 1;

    f32x4 acc[4][4] = {};

    const int srow = tid >> 3;
    const int scol = (tid & 7) * 4;

    #pragma unroll
    for (int t = 0; t < 5; ++t) {
        const int mask = (t == 0) ? 0 : (1 << (t - 1));
        const int s = p ^ mask;
        const float* xchunk = x  + (size_t)bm0 * INF + s * 256;
        const float* wchunk = hw + ((size_t)(t * 16 + s) * 256 + nh * 128) * 256;

        for (int k8 = 0; k8 < 8; ++k8) {
            const int kc = k8 * 32;
            #pragma unroll
            for (int i = 0; i < 4; ++i) {
                const int row = i * 32 + srow;
                float4 fa = *(const float4*)(xchunk + (size_t)row * INF + kc + scol);
                float4 fb = *(const float4*)(wchunk + (size_t)row * 256 + kc + scol);
                ushort4 ua, ub;
                ua.x = f2bf(fa.x); ua.y = f2bf(fa.y);
                ua.z = f2bf(fa.z); ua.w = f2bf(fa.w);
                ub.x = f2bf(fb.x); ub.y = f2bf(fb.y);
                ub.z = f2bf(fb.z); ub.w = f2bf(fb.w);
                *(ushort4*)&As[row][scol] = ua;
                *(ushort4*)&Bs[row][scol] = ub;
            }
            __syncthreads();

            short8 a[4], b[4];
            #pragma unroll
            for (int mi = 0; mi < 4; ++mi)
                a[mi] = *(const short8*)&As[wr * 64 + mi * 16 + (lane & 15)][(lane >> 4) * 8];
            #pragma unroll
            for (int nj = 0; nj < 4; ++nj)
                b[nj] = *(const short8*)&Bs[wc * 64 + nj * 16 + (lane & 15)][(lane >> 4) * 8];

            #pragma unroll
            for (int mi = 0; mi < 4; ++mi)
                #pragma unroll
                for (int nj = 0; nj < 4; ++nj)
                    acc[mi][nj] = __builtin_amdgcn_mfma_f32_16x16x32_bf16(
                        a[mi], b[nj], acc[mi][nj], 0, 0, 0);

            __syncthreads();
        }
    }

    const int col0 = p * 256 + nh * 128 + wc * 64;
    #pragma unroll
    for (int nj = 0; nj < 4; ++nj) {
        const int col = col0 + nj * 16 + (lane & 15);
        const float bias = hb[col];
        #pragma unroll
        for (int mi = 0; mi < 4; ++mi) {
            #pragma unroll
            for (int r = 0; r < 4; ++r) {
                const int row = bm0 + wr * 64 + mi * 16 + (lane >> 4) * 4 + r;
                out[(size_t)row * 4096 + col] = acc[mi][nj][r] + bias;
            }
        }
    }
}

extern "C" void kernel_launch(void* const* d_in, const int* in_sizes, int n_in,
                              void* d_out, int out_size, void* d_ws, size_t ws_size,
                              hipStream_t stream) {
    const float* x  = (const float*)d_in[0];   // [8192, 4096]
    const float* hw = (const float*)d_in[1];   // [5, 16, 256, 256]
    const float* hb = (const float*)d_in[2];   // [4096]
    float* out = (float*)d_out;                // [8192, 4096]

    const size_t NX = 8192ull * 4096;
    const size_t NW = 5ull * 16 * 256 * 256;
    const size_t need = (NX + NW) * sizeof(unsigned short);

    if (ws_size >= need) {
        unsigned short* xb = (unsigned short*)d_ws;
        unsigned short* wb = xb + NX;
        cvt_bf16<<<2048, 256, 0, stream>>>(x, hw, xb, wb);
        hipError_t e = hipFuncSetAttribute((const void*)hcl_gemm8p,
                                           hipFuncAttributeMaxDynamicSharedMemorySize,
                                           131072);
        if (e == hipSuccess) {
            dim3 grid(8192 / 256, 16);
            hcl_gemm8p<<<grid, 512, 131072, stream>>>(xb, wb, hb, out);
        } else {
            dim3 grid(8192 / 128, 16);
            hcl_gemm4<<<grid, 256, 3 * BUFB4, stream>>>(xb, wb, hb, out);
        }
    } else {
        dim3 grid(8192 / 128, 32);
        hcl_mfma_fused<<<grid, 256, 0, stream>>>(x, hw, hb, out);
    }
}

// Round 9
// 153.530 us; speedup vs baseline: 1.8351x; 1.8351x over previous
//
#include <hip/hip_runtime.h>

typedef __attribute__((ext_vector_type(8))) short short8;
typedef __attribute__((ext_vector_type(4))) float f32x4;

#define INF 4096

#define AS1 __attribute__((address_space(1)))
#define AS3 __attribute__((address_space(3)))

__device__ __forceinline__ unsigned short f2bf(float f) {
    unsigned int u = __float_as_uint(f);
    u += 0x7FFFu + ((u >> 16) & 1u);
    return (unsigned short)(u >> 16);
}

__device__ __forceinline__ void gl_lds16(const unsigned short* g, void* l) {
    __builtin_amdgcn_global_load_lds((const AS1 void*)g, (AS3 void*)l, 16, 0, 0);
}

// swizzle within 1KB blocks: XOR byte bits {4,5,6} with bits {7,8,9}.
// Involution, 16B-preserving. For [128][64]bf16 regions (128B rows) this
// spreads the stride-128B fragment reads across the row. R8-verified (0 confl).
__device__ __forceinline__ int swz7(int b) { return b ^ ((b >> 3) & 0x70); }
// 64B-row variant used by the fallback kernel (R4/R5-verified)
__device__ __forceinline__ int swz6(int b) { return b ^ ((b >> 3) & 0x30); }

#define BAR()   __builtin_amdgcn_s_barrier()
#define SB0()   __builtin_amdgcn_sched_barrier(0)

// ---------------- prepass: fp32 -> bf16 for x and hw ----------------
__global__ __launch_bounds__(256)
void cvt_bf16(const float* __restrict__ x, const float* __restrict__ hw,
              unsigned short* __restrict__ xb, unsigned short* __restrict__ wb)
{
    const long long NX = 8192LL * 4096;
    const long long NW = 5LL * 16 * 256 * 256;
    const long long total8 = (NX + NW) / 8;
    for (long long i = (long long)blockIdx.x * 256 + threadIdx.x; i < total8;
         i += (long long)gridDim.x * 256) {
        long long e = i * 8;
        const float* src;
        unsigned short* dst;
        long long off;
        if (e < NX) { src = x;  dst = xb; off = e; }
        else        { src = hw; dst = wb; off = e - NX; }
        float4 f0 = *(const float4*)(src + off);
        float4 f1 = *(const float4*)(src + off + 4);
        ushort4 u0, u1;
        u0.x = f2bf(f0.x); u0.y = f2bf(f0.y); u0.z = f2bf(f0.z); u0.w = f2bf(f0.w);
        u1.x = f2bf(f1.x); u1.y = f2bf(f1.y); u1.z = f2bf(f1.z); u1.w = f2bf(f1.w);
        *(ushort4*)(dst + off)     = u0;
        *(ushort4*)(dst + off + 4) = u1;
    }
}

// ======== main GEMM: 256x256 tile, 8 waves, BK=64, 2-buffer counted vmcnt ========
// R4/R5 loop structure (best measured) at BK=64: per K-tile one stage burst
// (8 gl_lds), one vmcnt(8) gate (next tile stays in flight; landing slack =
// a full compute phase), 2 barriers, compiler-scheduled compute (24 ds_read_b128
// + 64 MFMA per wave). LDS: 2 bufs x 64KB; regions per buf: 0=A rows0-127,
// 1=A rows128-255, 2=B cols0-127, 3=B cols128-255; each [128][64]bf16 swz7.
__global__ __launch_bounds__(512, 2)
void hcl_gemm64(const unsigned short* __restrict__ xb,
                const unsigned short* __restrict__ wb,
                const float* __restrict__ hb,
                float* __restrict__ out)
{
    extern __shared__ char lds[];   // 131072

    const int tid  = threadIdx.x;       // 0..511
    const int lane = tid & 63;
    const int wave = tid >> 6;          // 0..7
    const int wr   = wave >> 2;         // 0..1  m-half
    const int wcn  = wave & 3;          // 0..3  n-quarter
    const int ln15 = lane & 15;
    const int hi   = lane >> 4;

    const int bm0 = blockIdx.x * 256;
    const int p   = blockIdx.y;

    // fragment byte offsets within a buffer (ks=0; ks=1 is ^64: bit6 is not a
    // swz7 source bit, so swz7(x+64)=swz7(x)^64) [R8-verified]
    int offA[8], offB[4];
    #pragma unroll
    for (int mf = 0; mf < 8; ++mf)
        offA[mf] = wr * 16384 + swz7((mf * 16 + ln15) * 128 + hi * 16);
    #pragma unroll
    for (int nf = 0; nf < 4; ++nf)
        offB[nf] = 32768 + (wcn >> 1) * 16384 +
                   swz7(((wcn & 1) * 64 + nf * 16 + ln15) * 128 + hi * 16);

    // staging source geometry: inst j writes phys = j*8192 + tid*16 (linear),
    // global source element = logical swz7(phys) within the 16KB region
    int srow[2], skcol[2];
    #pragma unroll
    for (int j = 0; j < 2; ++j) {
        int L = swz7(j * 8192 + tid * 16);
        srow[j]  = L >> 7;
        skcol[j] = (L & 127) >> 1;
    }

    f32x4 acc[8][4] = {};

    auto STAGE = [&](int kt, int reg) {   // reg: 0=A0,1=A1,2=B0,3=B1
        if (kt >= 20) return;
        const int t  = kt >> 2;
        const int s  = p ^ ((1 << t) >> 1);
        const int k0 = (kt & 3) * 64;
        char* dst = lds + (kt & 1) * 65536 + reg * 16384 + tid * 16;
        if (reg < 2) {
            const unsigned short* g = xb + (size_t)(bm0 + reg * 128) * INF + s * 256 + k0;
            gl_lds16(g + (size_t)srow[0] * INF + skcol[0], dst);
            gl_lds16(g + (size_t)srow[1] * INF + skcol[1], dst + 8192);
        } else {
            const unsigned short* g = wb + ((size_t)(t * 16 + s) << 16) + (reg - 2) * 32768 + k0;
            gl_lds16(g + (size_t)srow[0] * 256 + skcol[0], dst);
            gl_lds16(g + (size_t)srow[1] * 256 + skcol[1], dst + 8192);
        }
    };

    short8 fa[8], fb0[4], fb1[4];
    auto LDA = [&](int qm, int buf) {      // 8 ds_read_b128 into fa (K=64)
        const char* L = lds + buf * 65536;
        #pragma unroll
        for (int m = 0; m < 4; ++m) {
            fa[m * 2 + 0] = *(const short8*)(L + offA[qm * 4 + m]);
            fa[m * 2 + 1] = *(const short8*)(L + (offA[qm * 4 + m] ^ 64));
        }
    };
    auto LDB0 = [&](int buf) {             // qn0 -> fb0
        const char* L = lds + buf * 65536;
        #pragma unroll
        for (int n = 0; n < 2; ++n) {
            fb0[n * 2 + 0] = *(const short8*)(L + offB[n]);
            fb0[n * 2 + 1] = *(const short8*)(L + (offB[n] ^ 64));
        }
    };
    auto LDB1 = [&](int buf) {             // qn1 -> fb1
        const char* L = lds + buf * 65536;
        #pragma unroll
        for (int n = 0; n < 2; ++n) {
            fb1[n * 2 + 0] = *(const short8*)(L + offB[2 + n]);
            fb1[n * 2 + 1] = *(const short8*)(L + (offB[2 + n] ^ 64));
        }
    };
    auto MM0 = [&](int qm) {               // quadrant (qm, qn0) with fb0
        __builtin_amdgcn_s_setprio(1);
        #pragma unroll
        for (int m = 0; m < 4; ++m)
            #pragma unroll
            for (int n = 0; n < 2; ++n)
                #pragma unroll
                for (int ks = 0; ks < 2; ++ks)
                    acc[qm * 4 + m][n] = __builtin_amdgcn_mfma_f32_16x16x32_bf16(
                        fa[m * 2 + ks], fb0[n * 2 + ks], acc[qm * 4 + m][n], 0, 0, 0);
        __builtin_amdgcn_s_setprio(0);
    };
    auto MM1 = [&](int qm) {               // quadrant (qm, qn1) with fb1
        __builtin_amdgcn_s_setprio(1);
        #pragma unroll
        for (int m = 0; m < 4; ++m)
            #pragma unroll
            for (int n = 0; n < 2; ++n)
                #pragma unroll
                for (int ks = 0; ks < 2; ++ks)
                    acc[qm * 4 + m][2 + n] = __builtin_amdgcn_mfma_f32_16x16x32_bf16(
                        fa[m * 2 + ks], fb1[n * 2 + ks], acc[qm * 4 + m][2 + n], 0, 0, 0);
        __builtin_amdgcn_s_setprio(0);
    };

    // prologue: T0 -> buf0 (8 loads)
    STAGE(0, 0); STAGE(0, 1); STAGE(0, 2); STAGE(0, 3);

    for (int kt = 0; kt < 20; ++kt) {
        // stage next tile into the other buffer (kt=19 -> guarded no-op)
        STAGE(kt + 1, 0); STAGE(kt + 1, 1); STAGE(kt + 1, 2); STAGE(kt + 1, 3);
        // gate: current tile landed; next tile's 8 loads stay in flight
        if (kt < 19) { asm volatile("s_waitcnt vmcnt(8)" ::: "memory"); }
        else         { asm volatile("s_waitcnt vmcnt(0)" ::: "memory"); }
        BAR(); SB0();
        // compute K=64 on current buffer; compiler schedules ds_read<->MFMA
        const int buf = kt & 1;
        LDB0(buf); LDB1(buf); LDA(0, buf);
        MM0(0); MM1(0);
        LDA(1, buf);
        MM1(1); MM0(1);
        BAR(); SB0();
    }

    // epilogue: C/D layout col = lane&15, row = (lane>>4)*4 + r  [R4-verified]
    const int col0 = p * 256 + wcn * 64;
    #pragma unroll
    for (int nf = 0; nf < 4; ++nf) {
        const int col = col0 + nf * 16 + ln15;
        const float bias = hb[col];
        #pragma unroll
        for (int mf = 0; mf < 8; ++mf) {
            #pragma unroll
            for (int r = 0; r < 4; ++r) {
                const int row = bm0 + wr * 128 + mf * 16 + hi * 4 + r;
                out[(size_t)row * 4096 + col] = acc[mf][nf][r] + bias;
            }
        }
    }
}

// -------- fallback GEMM (R5, proven): 128x256 tile, 4 waves, 3-buffer --------
#define NKT4 40
#define BUFB4 24576
__global__ __launch_bounds__(256, 2)
void hcl_gemm4(const unsigned short* __restrict__ xb,
               const unsigned short* __restrict__ wb,
               const float* __restrict__ hb,
               float* __restrict__ out)
{
    extern __shared__ unsigned short lds4[];

    const int tid  = threadIdx.x;
    const int lane = tid & 63;
    const int wave = tid >> 6;
    const int ln15 = lane & 15;
    const int hi   = lane >> 4;

    const int bm0 = blockIdx.x * 128;
    const int p   = blockIdx.y;

    int rj[4], cj[4];
    #pragma unroll
    for (int j = 0; j < 4; ++j) {
        int g = swz6(j * 4096 + tid * 16);
        rj[j] = g >> 6;
        cj[j] = (g & 63) >> 1;
    }

    int offA[8], offB[4];
    #pragma unroll
    for (int mf = 0; mf < 8; ++mf)
        offA[mf] = swz6((mf * 16 + ln15) * 64 + hi * 16);
    #pragma unroll
    for (int nf = 0; nf < 4; ++nf)
        offB[nf] = swz6((wave * 64 + nf * 16 + ln15) * 64 + hi * 16);

    f32x4 acc[8][4] = {};

    auto STAGE = [&](int kt, int buf) {
        const int t = kt >> 3;
        const int s = p ^ ((1 << t) >> 1);
        const unsigned short* ga = xb + (size_t)bm0 * INF + s * 256 + (kt & 7) * 32;
        const unsigned short* gb = wb + ((size_t)(t * 16 + s) << 16) + (kt & 7) * 32;
        char* lb = (char*)lds4 + buf * BUFB4 + wave * 1024;
        gl_lds16(ga + (size_t)rj[0] * INF + cj[0], lb);
        gl_lds16(ga + (size_t)rj[1] * INF + cj[1], lb + 4096);
        gl_lds16(gb + (size_t)rj[0] * 256 + cj[0], lb + 8192);
        gl_lds16(gb + (size_t)rj[1] * 256 + cj[1], lb + 8192 + 4096);
        gl_lds16(gb + (size_t)rj[2] * 256 + cj[2], lb + 8192 + 8192);
        gl_lds16(gb + (size_t)rj[3] * 256 + cj[3], lb + 8192 + 12288);
    };

    auto COMPUTE = [&](int buf) {
        const char* LA = (const char*)lds4 + buf * BUFB4;
        const char* LB = LA + 8192;
        short8 fa[8], fb[4];
        #pragma unroll
        for (int nf = 0; nf < 4; ++nf) fb[nf] = *(const short8*)(LB + offB[nf]);
        #pragma unroll
        for (int mf = 0; mf < 8; ++mf) fa[mf] = *(const short8*)(LA + offA[mf]);
        __builtin_amdgcn_s_setprio(1);
        #pragma unroll
        for (int mf = 0; mf < 8; ++mf)
            #pragma unroll
            for (int nf = 0; nf < 4; ++nf)
                acc[mf][nf] = __builtin_amdgcn_mfma_f32_16x16x32_bf16(
                    fa[mf], fb[nf], acc[mf][nf], 0, 0, 0);
        __builtin_amdgcn_s_setprio(0);
    };

    STAGE(0, 0);
    STAGE(1, 1);
    for (int kt = 0; kt < NKT4 - 2; ++kt) {
        STAGE(kt + 2, (kt + 2) % 3);
        asm volatile("s_waitcnt vmcnt(12)" ::: "memory");
        BAR(); SB0();
        COMPUTE(kt % 3);
        BAR(); SB0();
    }
    asm volatile("s_waitcnt vmcnt(6)" ::: "memory");
    BAR(); SB0();
    COMPUTE((NKT4 - 2) % 3);
    BAR(); SB0();
    asm volatile("s_waitcnt vmcnt(0)" ::: "memory");
    BAR(); SB0();
    COMPUTE((NKT4 - 1) % 3);

    const int col0 = p * 256 + wave * 64;
    #pragma unroll
    for (int nf = 0; nf < 4; ++nf) {
        const int col = col0 + nf * 16 + ln15;
        const float bias = hb[col];
        #pragma unroll
        for (int mf = 0; mf < 8; ++mf) {
            #pragma unroll
            for (int r = 0; r < 4; ++r) {
                const int row = bm0 + mf * 16 + hi * 4 + r;
                out[(size_t)row * 4096 + col] = acc[mf][nf][r] + bias;
            }
        }
    }
}

// ---------------- fallback (fused) if ws too small ----------------
__global__ __launch_bounds__(256)
void hcl_mfma_fused(const float* __restrict__ x,
                    const float* __restrict__ hw,
                    const float* __restrict__ hb,
                    float* __restrict__ out)
{
    __shared__ unsigned short As[128][32];
    __shared__ unsigned short Bs[128][32];

    const int tid  = threadIdx.x;
    const int lane = tid & 63;
    const int wave = tid >> 6;
    const int wr   = wave >> 1, wc = wave & 1;

    const int bm0 = blockIdx.x * 128;
    const int p   = blockIdx.y >> 1;
    const int nh  = blockIdx.y & 1;

    f32x4 acc[4][4] = {};

    const int srow = tid >> 3;
    const int scol = (tid & 7) * 4;

    #pragma unroll
    for (int t = 0; t < 5; ++t) {
        const int mask = (t == 0) ? 0 : (1 << (t - 1));
        const int s = p ^ mask;
        const float* xchunk = x  + (size_t)bm0 * INF + s * 256;
        const float* wchunk = hw + ((size_t)(t * 16 + s) * 256 + nh * 128) * 256;

        for (int k8 = 0; k8 < 8; ++k8) {
            const int kc = k8 * 32;
            #pragma unroll
            for (int i = 0; i < 4; ++i) {
                const int row = i * 32 + srow;
                float4 fa = *(const float4*)(xchunk + (size_t)row * INF + kc + scol);
                float4 fb = *(const float4*)(wchunk + (size_t)row * 256 + kc + scol);
                ushort4 ua, ub;
                ua.x = f2bf(fa.x); ua.y = f2bf(fa.y);
                ua.z = f2bf(fa.z); ua.w = f2bf(fa.w);
                ub.x = f2bf(fb.x); ub.y = f2bf(fb.y);
                ub.z = f2bf(fb.z); ub.w = f2bf(fb.w);
                *(ushort4*)&As[row][scol] = ua;
                *(ushort4*)&Bs[row][scol] = ub;
            }
            __syncthreads();

            short8 a[4], b[4];
            #pragma unroll
            for (int mi = 0; mi < 4; ++mi)
                a[mi] = *(const short8*)&As[wr * 64 + mi * 16 + (lane & 15)][(lane >> 4) * 8];
            #pragma unroll
            for (int nj = 0; nj < 4; ++nj)
                b[nj] = *(const short8*)&Bs[wc * 64 + nj * 16 + (lane & 15)][(lane >> 4) * 8];

            #pragma unroll
            for (int mi = 0; mi < 4; ++mi)
                #pragma unroll
                for (int nj = 0; nj < 4; ++nj)
                    acc[mi][nj] = __builtin_amdgcn_mfma_f32_16x16x32_bf16(
                        a[mi], b[nj], acc[mi][nj], 0, 0, 0);

            __syncthreads();
        }
    }

    const int col0 = p * 256 + nh * 128 + wc * 64;
    #pragma unroll
    for (int nj = 0; nj < 4; ++nj) {
        const int col = col0 + nj * 16 + (lane & 15);
        const float bias = hb[col];
        #pragma unroll
        for (int mi = 0; mi < 4; ++mi) {
            #pragma unroll
            for (int r = 0; r < 4; ++r) {
                const int row = bm0 + wr * 64 + mi * 16 + (lane >> 4) * 4 + r;
                out[(size_t)row * 4096 + col] = acc[mi][nj][r] + bias;
            }
        }
    }
}

extern "C" void kernel_launch(void* const* d_in, const int* in_sizes, int n_in,
                              void* d_out, int out_size, void* d_ws, size_t ws_size,
                              hipStream_t stream) {
    const float* x  = (const float*)d_in[0];   // [8192, 4096]
    const float* hw = (const float*)d_in[1];   // [5, 16, 256, 256]
    const float* hb = (const float*)d_in[2];   // [4096]
    float* out = (float*)d_out;                // [8192, 4096]

    const size_t NX = 8192ull * 4096;
    const size_t NW = 5ull * 16 * 256 * 256;
    const size_t need = (NX + NW) * sizeof(unsigned short);

    if (ws_size >= need) {
        unsigned short* xb = (unsigned short*)d_ws;
        unsigned short* wb = xb + NX;
        cvt_bf16<<<2048, 256, 0, stream>>>(x, hw, xb, wb);
        hipError_t e = hipFuncSetAttribute((const void*)hcl_gemm64,
                                           hipFuncAttributeMaxDynamicSharedMemorySize,
                                           131072);
        if (e == hipSuccess) {
            dim3 grid(8192 / 256, 16);
            hcl_gemm64<<<grid, 512, 131072, stream>>>(xb, wb, hb, out);
        } else {
            dim3 grid(8192 / 128, 16);
            hcl_gemm4<<<grid, 256, 3 * BUFB4, stream>>>(xb, wb, hb, out);
        }
    } else {
        dim3 grid(8192 / 128, 32);
        hcl_mfma_fused<<<grid, 256, 0, stream>>>(x, hw, hb, out);
    }
}